// Round 7
// baseline (1513.161 us; speedup 1.0000x reference)
//
#include <hip/hip_runtime.h>

#define N_NODES 100000
#define N_EDGES 1600000
#define NBKT 196          // ceil(100000 / 512)
#define BKT_SHIFT 9
#define BKT_MASK 511

typedef __attribute__((ext_vector_type(8))) short short8;
typedef __attribute__((ext_vector_type(4))) float float4v;

__device__ __forceinline__ unsigned short f2bf(float f) {  // RNE
  unsigned u = __float_as_uint(f);
  return (unsigned short)((u + 0x7fffu + ((u >> 16) & 1u)) >> 16);
}
__device__ __forceinline__ float bflo(unsigned d) { return __uint_as_float(d << 16); }
__device__ __forceinline__ float bfhi(unsigned d) { return __uint_as_float(d & 0xffff0000u); }

// ---- binning: edges grouped by 512-node dst bucket -------------------------

__global__ void kA_count(const int* __restrict__ dst, int* __restrict__ blkCnt) {
  __shared__ int hist[NBKT];
  for (int t = threadIdx.x; t < NBKT; t += 256) hist[t] = 0;
  __syncthreads();
  const int chunk = (N_EDGES + gridDim.x - 1) / gridDim.x;
  const int e0 = blockIdx.x * chunk;
  const int e1 = min(e0 + chunk, N_EDGES);
  for (int e = e0 + threadIdx.x; e < e1; e += 256)
    atomicAdd(&hist[dst[e] >> BKT_SHIFT], 1);
  __syncthreads();
  for (int t = threadIdx.x; t < NBKT; t += 256)
    blkCnt[t * 256 + blockIdx.x] = hist[t];
}

__global__ void kA_scan1(int* __restrict__ blkCnt, int* __restrict__ bktTot) {
  const int b = blockIdx.x;
  const int tid = threadIdx.x, lane = tid & 63, w = tid >> 6;
  int v = blkCnt[b * 256 + tid];
  int inc = v;
  #pragma unroll
  for (int d = 1; d < 64; d <<= 1) { int y = __shfl_up(inc, d); if (lane >= d) inc += y; }
  __shared__ int wtot[4];
  if (lane == 63) wtot[w] = inc;
  __syncthreads();
  int base = 0;
  for (int j = 0; j < w; j++) base += wtot[j];
  blkCnt[b * 256 + tid] = base + inc - v;
  if (tid == 255) bktTot[b] = base + inc;
}

__global__ void kA_scan2(const int* __restrict__ bktTot, int* __restrict__ bktStart) {
  int lane = threadIdx.x;
  int running = 0;
  for (int base = 0; base < NBKT; base += 64) {
    int i = base + lane;
    int v = (i < NBKT) ? bktTot[i] : 0;
    int inc = v;
    #pragma unroll
    for (int d = 1; d < 64; d <<= 1) { int y = __shfl_up(inc, d); if (lane >= d) inc += y; }
    if (i < NBKT) bktStart[i] = running + inc - v;
    running += __shfl(inc, 63);
  }
}

__global__ void kA_scatter(const int* __restrict__ src, const int* __restrict__ dst,
                           const int* __restrict__ blkCnt, const int* __restrict__ bktStart,
                           int* __restrict__ binned) {
  __shared__ int curb[NBKT];
  for (int t = threadIdx.x; t < NBKT; t += 256)
    curb[t] = bktStart[t] + blkCnt[t * 256 + blockIdx.x];
  __syncthreads();
  const int chunk = (N_EDGES + gridDim.x - 1) / gridDim.x;
  const int e0 = blockIdx.x * chunk;
  const int e1 = min(e0 + chunk, N_EDGES);
  for (int e = e0 + threadIdx.x; e < e1; e += 256) {
    int d = dst[e];
    int s = src[e];
    int b = d >> BKT_SHIFT;
    int p = atomicAdd(&curb[b], 1);
    binned[p] = s | ((d & BKT_MASK) << 17);   // src:17 bits | dlocal:9 bits
  }
}

// ---- f32 -> bf16 table conversion ------------------------------------------

__global__ void k_cvt(const float* __restrict__ in, unsigned short* __restrict__ outb) {
  int i = blockIdx.x * blockDim.x + threadIdx.x;
  const int n4 = (N_NODES * 64) / 4;
  if (i < n4) {
    float4 v = ((const float4*)in)[i];
    unsigned d0 = ((unsigned)f2bf(v.y) << 16) | f2bf(v.x);
    unsigned d1 = ((unsigned)f2bf(v.w) << 16) | f2bf(v.z);
    ((uint2*)outb)[i] = make_uint2(d0, d1);
  }
}

// ---- weight pre-swizzle into MFMA B-fragment order -------------------------

__global__ void k_wprep(const float* __restrict__ W0, const float* __restrict__ W1,
                        const float* __restrict__ W2, const float* __restrict__ W3,
                        unsigned short* __restrict__ F) {
  const float* W = (blockIdx.x == 0) ? W0 : (blockIdx.x == 1) ? W1
                 : (blockIdx.x == 2) ? W2 : W3;
  unsigned short* out = F + blockIdx.x * 4096;
  int lane = threadIdx.x;
  int col = lane & 15, kr = lane >> 4;
  #pragma unroll
  for (int kc = 0; kc < 2; kc++)
    #pragma unroll
    for (int nt = 0; nt < 4; nt++) {
      unsigned d[4];
      #pragma unroll
      for (int jj = 0; jj < 4; jj++) {
        float w0 = W[(kc * 32 + kr * 8 + 2 * jj)     * 64 + nt * 16 + col];
        float w1 = W[(kc * 32 + kr * 8 + 2 * jj + 1) * 64 + nt * 16 + col];
        d[jj] = ((unsigned)f2bf(w1) << 16) | f2bf(w0);
      }
      uint4* p = (uint4*)(out + ((kc * 4 + nt) * 64 + lane) * 8);
      *p = make_uint4(d[0], d[1], d[2], d[3]);
    }
}

// ---- fused bucket aggregation: LDS f32 accumulators, straight from binned --
// one block per 512-node bucket; 133 KB LDS acc (65-float rows -> ~2 lanes/bank)

__global__ __launch_bounds__(1024)
void k_aggx(const unsigned short* __restrict__ featb, const int* __restrict__ binned,
            const int* __restrict__ bktStart, const int* __restrict__ bktTot,
            unsigned short* __restrict__ aggb) {
  __shared__ float acc[512 * 65];
  __shared__ int cnt[512];
  const int tid = threadIdx.x;
  const int b = blockIdx.x;
  for (int i = tid; i < 512 * 65; i += 1024) acc[i] = 0.f;
  if (tid < 512) cnt[tid] = 0;
  __syncthreads();

  const int s0 = bktStart[b], ne = bktTot[b];
  const int lane = tid & 63, wib = tid >> 6;   // 16 waves
  const int r = lane >> 3, c = lane & 7;       // 8 edge slots x 8 feature octets

  for (int base = wib * 8; base < ne; base += 128) {
    int e = base + r;
    if (e < ne) {
      int pe = binned[s0 + e];
      int s  = pe & 0x1FFFF;
      int dl = pe >> 17;
      uint4 row = *(const uint4*)(featb + s * 64 + c * 8);
      float* a = &acc[dl * 65 + c * 8];
      atomicAdd(&a[0], bflo(row.x)); atomicAdd(&a[1], bfhi(row.x));
      atomicAdd(&a[2], bflo(row.y)); atomicAdd(&a[3], bfhi(row.y));
      atomicAdd(&a[4], bflo(row.z)); atomicAdd(&a[5], bfhi(row.z));
      atomicAdd(&a[6], bflo(row.w)); atomicAdd(&a[7], bfhi(row.w));
      if (c == 0) atomicAdd(&cnt[dl], 1);
    }
  }
  __syncthreads();

  // writeout: thread t -> node (t>>1), feature half (t&1)*32
  const int nl = tid >> 1, h = tid & 1;
  const int n = (b << BKT_SHIFT) + nl;
  if (n < N_NODES) {
    const int dg = cnt[nl];
    const float inv = (dg > 0) ? (1.0f / (float)dg) : 0.f;
    const float* a = &acc[nl * 65 + h * 32];
    unsigned short* dstp = aggb + n * 64 + h * 32;
    #pragma unroll
    for (int q = 0; q < 4; q++) {
      unsigned d0 = ((unsigned)f2bf(a[8 * q + 1] * inv) << 16) | f2bf(a[8 * q + 0] * inv);
      unsigned d1 = ((unsigned)f2bf(a[8 * q + 3] * inv) << 16) | f2bf(a[8 * q + 2] * inv);
      unsigned d2 = ((unsigned)f2bf(a[8 * q + 5] * inv) << 16) | f2bf(a[8 * q + 4] * inv);
      unsigned d3 = ((unsigned)f2bf(a[8 * q + 7] * inv) << 16) | f2bf(a[8 * q + 6] * inv);
      ((uint4*)dstp)[q] = make_uint4(d0, d1, d2, d3);
    }
  }
}

// ---- MFMA transform: out = self@Ws + agg@Wn + b ----------------------------

template <bool RELU, bool OUT_BF>
__global__ void k_xform(const unsigned short* __restrict__ selfb,
                        const unsigned short* __restrict__ aggb,
                        const unsigned short* __restrict__ wfS,
                        const unsigned short* __restrict__ wfN,
                        const float* __restrict__ bias,
                        float* __restrict__ outf, unsigned short* __restrict__ outb) {
  const int lane = threadIdx.x & 63;
  const int col = lane & 15, rr = lane >> 4;
  const int wid = (blockIdx.x * blockDim.x + threadIdx.x) >> 6;
  const int nw  = (gridDim.x * blockDim.x) >> 6;

  short8 bs[2][4], bn[2][4];
  #pragma unroll
  for (int kc = 0; kc < 2; kc++)
    #pragma unroll
    for (int nt = 0; nt < 4; nt++) {
      bs[kc][nt] = *(const short8*)(wfS + ((kc * 4 + nt) * 64 + lane) * 8);
      bn[kc][nt] = *(const short8*)(wfN + ((kc * 4 + nt) * 64 + lane) * 8);
    }
  float bv[4];
  #pragma unroll
  for (int nt = 0; nt < 4; nt++) bv[nt] = bias[nt * 16 + col];

  const int NT = N_NODES / 16;  // 6250
  for (int t = wid; t < NT; t += nw) {
    const int m = t * 16 + col;
    short8 as0 = *(const short8*)(selfb + m * 64 + rr * 8);
    short8 as1 = *(const short8*)(selfb + m * 64 + 32 + rr * 8);
    short8 aa0 = *(const short8*)(aggb + m * 64 + rr * 8);
    short8 aa1 = *(const short8*)(aggb + m * 64 + 32 + rr * 8);
    #pragma unroll
    for (int nt = 0; nt < 4; nt++) {
      float4v cfr = {bv[nt], bv[nt], bv[nt], bv[nt]};
      cfr = __builtin_amdgcn_mfma_f32_16x16x32_bf16(as0, bs[0][nt], cfr, 0, 0, 0);
      cfr = __builtin_amdgcn_mfma_f32_16x16x32_bf16(as1, bs[1][nt], cfr, 0, 0, 0);
      cfr = __builtin_amdgcn_mfma_f32_16x16x32_bf16(aa0, bn[0][nt], cfr, 0, 0, 0);
      cfr = __builtin_amdgcn_mfma_f32_16x16x32_bf16(aa1, bn[1][nt], cfr, 0, 0, 0);
      #pragma unroll
      for (int r2 = 0; r2 < 4; r2++) {
        int row = t * 16 + rr * 4 + r2;
        float v = cfr[r2];
        if (RELU) v = fmaxf(v, 0.f);
        if (OUT_BF) outb[row * 64 + nt * 16 + col] = f2bf(v);
        else        outf[row * 64 + nt * 16 + col] = v;
      }
    }
  }
}

// ---- launch ----------------------------------------------------------------

extern "C" void kernel_launch(void* const* d_in, const int* in_sizes, int n_in,
                              void* d_out, int out_size, void* d_ws, size_t ws_size,
                              hipStream_t stream) {
  const float* x   = (const float*)d_in[0];
  const int*   src = (const int*)d_in[1];
  const int*   dst = (const int*)d_in[2];
  const float* Ws1 = (const float*)d_in[3];
  const float* Wn1 = (const float*)d_in[4];
  const float* b1  = (const float*)d_in[5];
  const float* Ws2 = (const float*)d_in[6];
  const float* Wn2 = (const float*)d_in[7];
  const float* b2  = (const float*)d_in[8];

  char* ws = (char*)d_ws;   // ws_size = 256 MiB; no aliasing needed
  int*            blkCnt   = (int*)(ws + 0);          // NBKT*256 ints
  int*            bktTot   = (int*)(ws + 262144);     // NBKT ints
  int*            bktStart = (int*)(ws + 266240);     // NBKT ints
  unsigned short* wf       = (unsigned short*)(ws + 270336);   // 32 KB
  int*            binned   = (int*)(ws + 303104);     // E ints (6.4 MB)
  unsigned short* xbf      = (unsigned short*)(ws + 6703104);  // N*64 bf16
  unsigned short* hbf      = (unsigned short*)(ws + 19503104); // N*64 bf16
  unsigned short* agg1     = (unsigned short*)(ws + 32303104); // N*64 bf16
  unsigned short* agg2     = (unsigned short*)(ws + 45103104); // N*64 bf16

  kA_count<<<256, 256, 0, stream>>>(dst, blkCnt);
  kA_scan1<<<NBKT, 256, 0, stream>>>(blkCnt, bktTot);
  kA_scan2<<<1, 64, 0, stream>>>(bktTot, bktStart);
  kA_scatter<<<256, 256, 0, stream>>>(src, dst, blkCnt, bktStart, binned);

  k_cvt<<<(N_NODES * 16 + 255) / 256, 256, 0, stream>>>(x, xbf);
  k_wprep<<<4, 64, 0, stream>>>(Ws1, Wn1, Ws2, Wn2, wf);

  k_aggx<<<NBKT, 1024, 0, stream>>>(xbf, binned, bktStart, bktTot, agg1);
  k_xform<true, true><<<1024, 256, 0, stream>>>(xbf, agg1, wf + 0 * 4096, wf + 1 * 4096,
                                                b1, nullptr, hbf);
  k_aggx<<<NBKT, 1024, 0, stream>>>(hbf, binned, bktStart, bktTot, agg2);
  k_xform<false, false><<<1024, 256, 0, stream>>>(hbf, agg2, wf + 2 * 4096, wf + 3 * 4096,
                                                  b2, (float*)d_out, nullptr);
}

// Round 8
// 244.084 us; speedup vs baseline: 6.1994x; 6.1994x over previous
//
#include <hip/hip_runtime.h>

#define N_NODES 100000
#define N_EDGES 1600000
#define NBKT 196          // ceil(100000 / 512)
#define BKT_SHIFT 9
#define BKT_MASK 511

typedef __attribute__((ext_vector_type(8))) short short8;
typedef __attribute__((ext_vector_type(4))) float float4v;

__device__ __forceinline__ unsigned short f2bf(float f) {  // RNE
  unsigned u = __float_as_uint(f);
  return (unsigned short)((u + 0x7fffu + ((u >> 16) & 1u)) >> 16);
}
__device__ __forceinline__ float bflo(unsigned d) { return __uint_as_float(d << 16); }
__device__ __forceinline__ float bfhi(unsigned d) { return __uint_as_float(d & 0xffff0000u); }

// ---- binning: edges grouped by 512-node dst bucket -------------------------

__global__ void kA_count(const int* __restrict__ dst, int* __restrict__ blkCnt) {
  __shared__ int hist[NBKT];
  for (int t = threadIdx.x; t < NBKT; t += 256) hist[t] = 0;
  __syncthreads();
  const int chunk = (N_EDGES + gridDim.x - 1) / gridDim.x;
  const int e0 = blockIdx.x * chunk;
  const int e1 = min(e0 + chunk, N_EDGES);
  for (int e = e0 + threadIdx.x; e < e1; e += 256)
    atomicAdd(&hist[dst[e] >> BKT_SHIFT], 1);
  __syncthreads();
  for (int t = threadIdx.x; t < NBKT; t += 256)
    blkCnt[t * 256 + blockIdx.x] = hist[t];
}

__global__ void kA_scan1(int* __restrict__ blkCnt, int* __restrict__ bktTot) {
  const int b = blockIdx.x;
  const int tid = threadIdx.x, lane = tid & 63, w = tid >> 6;
  int v = blkCnt[b * 256 + tid];
  int inc = v;
  #pragma unroll
  for (int d = 1; d < 64; d <<= 1) { int y = __shfl_up(inc, d); if (lane >= d) inc += y; }
  __shared__ int wtot[4];
  if (lane == 63) wtot[w] = inc;
  __syncthreads();
  int base = 0;
  for (int j = 0; j < w; j++) base += wtot[j];
  blkCnt[b * 256 + tid] = base + inc - v;
  if (tid == 255) bktTot[b] = base + inc;
}

__global__ void kA_scan2(const int* __restrict__ bktTot, int* __restrict__ bktStart) {
  int lane = threadIdx.x;
  int running = 0;
  for (int base = 0; base < NBKT; base += 64) {
    int i = base + lane;
    int v = (i < NBKT) ? bktTot[i] : 0;
    int inc = v;
    #pragma unroll
    for (int d = 1; d < 64; d <<= 1) { int y = __shfl_up(inc, d); if (lane >= d) inc += y; }
    if (i < NBKT) bktStart[i] = running + inc - v;
    running += __shfl(inc, 63);
  }
}

__global__ void kA_scatter(const int* __restrict__ src, const int* __restrict__ dst,
                           const int* __restrict__ blkCnt, const int* __restrict__ bktStart,
                           int* __restrict__ binned) {
  __shared__ int curb[NBKT];
  for (int t = threadIdx.x; t < NBKT; t += 256)
    curb[t] = bktStart[t] + blkCnt[t * 256 + blockIdx.x];
  __syncthreads();
  const int chunk = (N_EDGES + gridDim.x - 1) / gridDim.x;
  const int e0 = blockIdx.x * chunk;
  const int e1 = min(e0 + chunk, N_EDGES);
  for (int e = e0 + threadIdx.x; e < e1; e += 256) {
    int d = dst[e];
    int s = src[e];
    int b = d >> BKT_SHIFT;
    int p = atomicAdd(&curb[b], 1);
    binned[p] = s | ((d & BKT_MASK) << 17);   // src:17 bits | dlocal:9 bits
  }
}

// ---- merged counting sort: hist + scan -> off, place -> esrc (one launch) --

__global__ void k_sort(const int* __restrict__ binned, const int* __restrict__ bktStart,
                       const int* __restrict__ bktTot,
                       int* __restrict__ off, int* __restrict__ esrc) {
  const int b = blockIdx.x;
  const int tid = threadIdx.x, lane = tid & 63, w = tid >> 6;
  __shared__ int cnt[512];
  __shared__ int pos[512];
  cnt[tid] = 0; cnt[tid + 256] = 0;
  __syncthreads();
  const int s0 = bktStart[b], ne = bktTot[b];
  for (int i = tid; i < ne; i += 256)
    atomicAdd(&cnt[binned[s0 + i] >> 17], 1);
  __syncthreads();
  // scan 512 counters: thread t owns nodes 2t, 2t+1
  int c0 = cnt[2 * tid], c1 = cnt[2 * tid + 1];
  int v = c0 + c1;
  int inc = v;
  #pragma unroll
  for (int d = 1; d < 64; d <<= 1) { int y = __shfl_up(inc, d); if (lane >= d) inc += y; }
  __shared__ int wtot[4];
  if (lane == 63) wtot[w] = inc;
  __syncthreads();
  int base = s0;
  for (int j = 0; j < w; j++) base += wtot[j];
  int ex = base + inc - v;  // global edge offset of node (b<<9)+2t
  pos[2 * tid] = ex;
  pos[2 * tid + 1] = ex + c0;
  int n0 = (b << BKT_SHIFT) + 2 * tid;
  if (n0 < N_NODES)     off[n0] = ex;
  if (n0 + 1 < N_NODES) off[n0 + 1] = ex + c0;
  if (b == NBKT - 1 && tid == 0) off[N_NODES] = N_EDGES;
  __syncthreads();
  // place (second binned read is L2-warm; esrc writes bucket-local)
  for (int i = tid; i < ne; i += 256) {
    int pe = binned[s0 + i];
    int p = atomicAdd(&pos[pe >> 17], 1);
    esrc[p] = pe & 0x1FFFF;
  }
}

// ---- f32 -> bf16 table conversion ------------------------------------------

__global__ void k_cvt(const float* __restrict__ in, unsigned short* __restrict__ outb) {
  int i = blockIdx.x * blockDim.x + threadIdx.x;
  const int n4 = (N_NODES * 64) / 4;
  if (i < n4) {
    float4 v = ((const float4*)in)[i];
    unsigned d0 = ((unsigned)f2bf(v.y) << 16) | f2bf(v.x);
    unsigned d1 = ((unsigned)f2bf(v.w) << 16) | f2bf(v.z);
    ((uint2*)outb)[i] = make_uint2(d0, d1);
  }
}

// ---- weight pre-swizzle into MFMA B-fragment order -------------------------

__global__ void k_wprep(const float* __restrict__ W0, const float* __restrict__ W1,
                        const float* __restrict__ W2, const float* __restrict__ W3,
                        unsigned short* __restrict__ F) {
  const float* W = (blockIdx.x == 0) ? W0 : (blockIdx.x == 1) ? W1
                 : (blockIdx.x == 2) ? W2 : W3;
  unsigned short* out = F + blockIdx.x * 4096;
  int lane = threadIdx.x;
  int col = lane & 15, kr = lane >> 4;
  #pragma unroll
  for (int kc = 0; kc < 2; kc++)
    #pragma unroll
    for (int nt = 0; nt < 4; nt++) {
      unsigned d[4];
      #pragma unroll
      for (int jj = 0; jj < 4; jj++) {
        float w0 = W[(kc * 32 + kr * 8 + 2 * jj)     * 64 + nt * 16 + col];
        float w1 = W[(kc * 32 + kr * 8 + 2 * jj + 1) * 64 + nt * 16 + col];
        d[jj] = ((unsigned)f2bf(w1) << 16) | f2bf(w0);
      }
      uint4* p = (uint4*)(out + ((kc * 4 + nt) * 64 + lane) * 8);
      *p = make_uint4(d[0], d[1], d[2], d[3]);
    }
}

// ---- pure aggregation: mean of neighbor bf16 rows (R6-proven) --------------

__global__ void k_agg(const unsigned short* __restrict__ featb,
                      const int* __restrict__ off, const int* __restrict__ esrc,
                      unsigned short* __restrict__ aggb) {
  const int lane = threadIdx.x & 63;
  const int r = lane >> 3;
  const int c = lane & 7;
  const int wid = (blockIdx.x * blockDim.x + threadIdx.x) >> 6;
  const int nw  = (gridDim.x * blockDim.x) >> 6;

  for (int n = wid; n < N_NODES; n += nw) {
    const int o0 = off[n], o1 = off[n + 1];
    float acc[8];
    #pragma unroll
    for (int j = 0; j < 8; j++) acc[j] = 0.f;

    int i = o0;
    for (; i + 16 <= o1; i += 16) {
      int sA = esrc[i + r];
      int sB = esrc[i + 8 + r];
      uint4 vA = *(const uint4*)(featb + sA * 64 + c * 8);
      uint4 vB = *(const uint4*)(featb + sB * 64 + c * 8);
      acc[0] += bflo(vA.x); acc[1] += bfhi(vA.x);
      acc[2] += bflo(vA.y); acc[3] += bfhi(vA.y);
      acc[4] += bflo(vA.z); acc[5] += bfhi(vA.z);
      acc[6] += bflo(vA.w); acc[7] += bfhi(vA.w);
      acc[0] += bflo(vB.x); acc[1] += bfhi(vB.x);
      acc[2] += bflo(vB.y); acc[3] += bfhi(vB.y);
      acc[4] += bflo(vB.z); acc[5] += bfhi(vB.z);
      acc[6] += bflo(vB.w); acc[7] += bfhi(vB.w);
    }
    if (i + 8 <= o1) {
      int s = esrc[i + r];
      uint4 v = *(const uint4*)(featb + s * 64 + c * 8);
      acc[0] += bflo(v.x); acc[1] += bfhi(v.x);
      acc[2] += bflo(v.y); acc[3] += bfhi(v.y);
      acc[4] += bflo(v.z); acc[5] += bfhi(v.z);
      acc[6] += bflo(v.w); acc[7] += bfhi(v.w);
      i += 8;
    }
    if (i < o1) {
      int e = i + r;
      if (e < o1) {
        int s = esrc[e];
        uint4 v = *(const uint4*)(featb + s * 64 + c * 8);
        acc[0] += bflo(v.x); acc[1] += bfhi(v.x);
        acc[2] += bflo(v.y); acc[3] += bfhi(v.y);
        acc[4] += bflo(v.z); acc[5] += bfhi(v.z);
        acc[6] += bflo(v.w); acc[7] += bfhi(v.w);
      }
    }
    #pragma unroll
    for (int m = 8; m <= 32; m <<= 1)
      #pragma unroll
      for (int j = 0; j < 8; j++) acc[j] += __shfl_xor(acc[j], m);

    const int dg = o1 - o0;
    const float inv = (dg > 0) ? (1.0f / (float)dg) : 0.f;
    if (r == 0) {
      unsigned d0 = ((unsigned)f2bf(acc[1] * inv) << 16) | f2bf(acc[0] * inv);
      unsigned d1 = ((unsigned)f2bf(acc[3] * inv) << 16) | f2bf(acc[2] * inv);
      unsigned d2 = ((unsigned)f2bf(acc[5] * inv) << 16) | f2bf(acc[4] * inv);
      unsigned d3 = ((unsigned)f2bf(acc[7] * inv) << 16) | f2bf(acc[6] * inv);
      *(uint4*)(aggb + n * 64 + c * 8) = make_uint4(d0, d1, d2, d3);
    }
  }
}

// ---- MFMA transform: out = self@Ws + agg@Wn + b ----------------------------

template <bool RELU, bool OUT_BF>
__global__ void k_xform(const unsigned short* __restrict__ selfb,
                        const unsigned short* __restrict__ aggb,
                        const unsigned short* __restrict__ wfS,
                        const unsigned short* __restrict__ wfN,
                        const float* __restrict__ bias,
                        float* __restrict__ outf, unsigned short* __restrict__ outb) {
  const int lane = threadIdx.x & 63;
  const int col = lane & 15, rr = lane >> 4;
  const int wid = (blockIdx.x * blockDim.x + threadIdx.x) >> 6;
  const int nw  = (gridDim.x * blockDim.x) >> 6;

  short8 bs[2][4], bn[2][4];
  #pragma unroll
  for (int kc = 0; kc < 2; kc++)
    #pragma unroll
    for (int nt = 0; nt < 4; nt++) {
      bs[kc][nt] = *(const short8*)(wfS + ((kc * 4 + nt) * 64 + lane) * 8);
      bn[kc][nt] = *(const short8*)(wfN + ((kc * 4 + nt) * 64 + lane) * 8);
    }
  float bv[4];
  #pragma unroll
  for (int nt = 0; nt < 4; nt++) bv[nt] = bias[nt * 16 + col];

  const int NT = N_NODES / 16;  // 6250
  for (int t = wid; t < NT; t += nw) {
    const int m = t * 16 + col;
    short8 as0 = *(const short8*)(selfb + m * 64 + rr * 8);
    short8 as1 = *(const short8*)(selfb + m * 64 + 32 + rr * 8);
    short8 aa0 = *(const short8*)(aggb + m * 64 + rr * 8);
    short8 aa1 = *(const short8*)(aggb + m * 64 + 32 + rr * 8);
    #pragma unroll
    for (int nt = 0; nt < 4; nt++) {
      float4v cfr = {bv[nt], bv[nt], bv[nt], bv[nt]};
      cfr = __builtin_amdgcn_mfma_f32_16x16x32_bf16(as0, bs[0][nt], cfr, 0, 0, 0);
      cfr = __builtin_amdgcn_mfma_f32_16x16x32_bf16(as1, bs[1][nt], cfr, 0, 0, 0);
      cfr = __builtin_amdgcn_mfma_f32_16x16x32_bf16(aa0, bn[0][nt], cfr, 0, 0, 0);
      cfr = __builtin_amdgcn_mfma_f32_16x16x32_bf16(aa1, bn[1][nt], cfr, 0, 0, 0);
      #pragma unroll
      for (int r2 = 0; r2 < 4; r2++) {
        int row = t * 16 + rr * 4 + r2;
        float v = cfr[r2];
        if (RELU) v = fmaxf(v, 0.f);
        if (OUT_BF) outb[row * 64 + nt * 16 + col] = f2bf(v);
        else        outf[row * 64 + nt * 16 + col] = v;
      }
    }
  }
}

// ---- launch ----------------------------------------------------------------

extern "C" void kernel_launch(void* const* d_in, const int* in_sizes, int n_in,
                              void* d_out, int out_size, void* d_ws, size_t ws_size,
                              hipStream_t stream) {
  const float* x   = (const float*)d_in[0];
  const int*   src = (const int*)d_in[1];
  const int*   dst = (const int*)d_in[2];
  const float* Ws1 = (const float*)d_in[3];
  const float* Wn1 = (const float*)d_in[4];
  const float* b1  = (const float*)d_in[5];
  const float* Ws2 = (const float*)d_in[6];
  const float* Wn2 = (const float*)d_in[7];
  const float* b2  = (const float*)d_in[8];

  char* ws = (char*)d_ws;
  int*            blkCnt   = (int*)(ws + 0);          // NBKT*256 ints
  int*            bktTot   = (int*)(ws + 262144);     // NBKT ints
  int*            bktStart = (int*)(ws + 266240);     // NBKT ints
  unsigned short* wf       = (unsigned short*)(ws + 270336);   // 32 KB
  int*            binned   = (int*)(ws + 303104);     // E ints (6.4 MB)
  int*            off      = (int*)(ws + 6703104);    // N+1 ints
  int*            esrc     = (int*)(ws + 7103488);    // E ints (6.4 MB)
  unsigned short* xbf      = (unsigned short*)(ws + 13503488);  // N*64 bf16
  unsigned short* hbf      = (unsigned short*)(ws + 26303488);  // N*64 bf16
  unsigned short* agg1     = (unsigned short*)(ws + 39103488);  // N*64 bf16
  unsigned short* agg2     = (unsigned short*)(ws + 51903488);  // N*64 bf16

  kA_count<<<256, 256, 0, stream>>>(dst, blkCnt);
  kA_scan1<<<NBKT, 256, 0, stream>>>(blkCnt, bktTot);
  kA_scan2<<<1, 64, 0, stream>>>(bktTot, bktStart);
  kA_scatter<<<256, 256, 0, stream>>>(src, dst, blkCnt, bktStart, binned);
  k_sort<<<NBKT, 256, 0, stream>>>(binned, bktStart, bktTot, off, esrc);

  k_cvt<<<(N_NODES * 16 + 255) / 256, 256, 0, stream>>>(x, xbf);
  k_wprep<<<4, 64, 0, stream>>>(Ws1, Wn1, Ws2, Wn2, wf);

  k_agg<<<2048, 256, 0, stream>>>(xbf, off, esrc, agg1);
  k_xform<true, true><<<1024, 256, 0, stream>>>(xbf, agg1, wf + 0 * 4096, wf + 1 * 4096,
                                                b1, nullptr, hbf);
  k_agg<<<2048, 256, 0, stream>>>(hbf, off, esrc, agg2);
  k_xform<false, false><<<1024, 256, 0, stream>>>(hbf, agg2, wf + 2 * 4096, wf + 3 * 4096,
                                                  b2, (float*)d_out, nullptr);
}